// Round 15
// baseline (255.573 us; speedup 1.0000x reference)
//
#include <hip/hip_runtime.h>

typedef unsigned short ushort;
typedef __attribute__((ext_vector_type(8))) __bf16 bf16x8;
typedef __attribute__((ext_vector_type(8))) ushort ushort8;
typedef __attribute__((ext_vector_type(4))) float f32x4;
typedef __attribute__((ext_vector_type(16))) float f32x16;
typedef __attribute__((ext_vector_type(4))) unsigned u32x4;

#define DM 2048
#define NH 16
#define DK 128
#define BATCH 2
#define SEQ 2048
#define MROWS (BATCH*SEQ)   // 4096

#define GLDS16(g, l) __builtin_amdgcn_global_load_lds(                         \
    (const __attribute__((address_space(1))) void*)(g),                        \
    (__attribute__((address_space(3))) void*)(l), 16, 0, 0)

__device__ __forceinline__ ushort f2bf(float f) {
  unsigned u = __builtin_bit_cast(unsigned, f);
  u += 0x7fffu + ((u >> 16) & 1u);
  return (ushort)(u >> 16);
}

__device__ __forceinline__ unsigned cvtpk(float lo, float hi) {
  unsigned r;
  asm("v_cvt_pk_bf16_f32 %0, %1, %2" : "=v"(r) : "v"(lo), "v"(hi));
  return r;
}

// permlane32_swap: a' = [a.lo32 | b.lo32], b' = [a.hi32 | b.hi32]
__device__ __forceinline__ void pswap(unsigned& a, unsigned& b) {
#if __has_builtin(__builtin_amdgcn_permlane32_swap)
  auto r = __builtin_amdgcn_permlane32_swap(a, b, false, false);
  a = r[0];
  b = r[1];
#else
  unsigned as = (unsigned)__shfl_xor((int)a, 32), bs = (unsigned)__shfl_xor((int)b, 32);
  bool hi = (threadIdx.x & 32) != 0;
  unsigned na = hi ? bs : a;
  unsigned nb = hi ? b : as;
  a = na;
  b = nb;
#endif
}

// ---------------- f32 -> bf16 convert (x + 4 weights, one launch) ----------------
__global__ __launch_bounds__(256) void cvt_all(const float* __restrict__ x,
                                               const float* __restrict__ w0,
                                               const float* __restrict__ w1,
                                               const float* __restrict__ w2,
                                               const float* __restrict__ w3,
                                               ushort* __restrict__ xb,
                                               ushort* __restrict__ o0,
                                               ushort* __restrict__ o1,
                                               ushort* __restrict__ o2,
                                               ushort* __restrict__ o3) {
  int b = blockIdx.x;
  const float* src;
  ushort* dst;
  int lb;
  if (b < 4096) { src = x; dst = xb; lb = b; }
  else {
    int wsel = (b - 4096) >> 11;
    lb = (b - 4096) & 2047;
    src = (wsel == 0) ? w0 : (wsel == 1) ? w1 : (wsel == 2) ? w2 : w3;
    dst = (wsel == 0) ? o0 : (wsel == 1) ? o1 : (wsel == 2) ? o2 : o3;
  }
  int i = lb * 256 + threadIdx.x;
  const float4* p = (const float4*)src;
  float4 a = p[2 * i], bq = p[2 * i + 1];
  ushort8 o;
  o[0] = f2bf(a.x); o[1] = f2bf(a.y); o[2] = f2bf(a.z); o[3] = f2bf(a.w);
  o[4] = f2bf(bq.x); o[5] = f2bf(bq.y); o[6] = f2bf(bq.z); o[7] = f2bf(bq.w);
  *(ushort8*)(dst + (size_t)8 * i) = o;
}

#define SWZ(r) (((r) ^ ((r) >> 2)) & 3)

// ---- fused QKV GEMM, BM=128, BK=32, 8 waves (2M x 4N), 2 BLOCKS/CU ----
// LDS = 2 x 32KB (A 128x32 + 3x B 128x32 per buffer) -> 64KB -> 2 blocks/CU:
// the per-tile vmcnt(0) drain is hidden by the co-resident block (m114 overlap).
// Granule swizzle c ^ SWZ(row) (involution: pre-swizzled global source +
// swizzled ds_read) spreads the 64B-row-stride frag reads across ~8 banks.
// launch_bounds(512,4) caps VGPR at 128 so 16 waves/CU fit.
// Epilogue: RoPE on Q/K (fast __sinf/__cosf) + V transposed via LDS (stride 137).
__global__ __launch_bounds__(512, 4) void gemmF_qkv(const ushort* __restrict__ A,
                                                    const ushort* __restrict__ W0,
                                                    const ushort* __restrict__ W1,
                                                    const ushort* __restrict__ W2,
                                                    ushort* __restrict__ Qo,
                                                    ushort* __restrict__ Ko,
                                                    ushort* __restrict__ Vt,
                                                    const int* __restrict__ tpos) {
  extern __shared__ ushort lds[];
  constexpr int NT = DM / 32;      // 64 K-tiles
  constexpr int BUFSZ = 16384;     // ushorts: A 128x32 + 3x B 128x32
  // 512 blocks; XCD-bijective swizzle (chunk 64) — round-5 spread mapping
  int f = ((int)blockIdx.x & 7) * 64 + ((int)blockIdx.x >> 3);
  int row0 = (f >> 4) * 128, col0 = (f & 15) * 128;
  const ushort* Bw[3] = {W0, W1, W2};
  const int tid = threadIdx.x;
  const int wid = tid >> 6, lane = tid & 63;
  const int l15 = lane & 15, lhi = lane >> 4;
  const int wm = wid >> 2, wn = wid & 3;

  f32x4 acc[4][6];
  const f32x4 z4 = {0.f, 0.f, 0.f, 0.f};
#pragma unroll
  for (int mq = 0; mq < 4; ++mq)
#pragma unroll
    for (int i = 0; i < 6; ++i) acc[mq][i] = z4;

  // staging: thread owns granule (sr, sc); global source pre-inverse-swizzled
  const int sr = tid >> 2, sc = tid & 3;
  const ushort* srcA0 = A + (size_t)(row0 + sr) * DM + ((sc ^ SWZ(sr)) * 8);
  const ushort* srcB0[3];
#pragma unroll
  for (int j = 0; j < 3; ++j)
    srcB0[j] = Bw[j] + (size_t)(col0 + sr) * DM + ((sc ^ SWZ(sr)) * 8);

  auto stage = [&](int kt, int buf) {
    GLDS16(srcA0 + kt * 32, &lds[buf * BUFSZ + wid * 512]);
#pragma unroll
    for (int j = 0; j < 3; ++j)
      GLDS16(srcB0[j] + kt * 32, &lds[buf * BUFSZ + 4096 + j * 4096 + wid * 512]);
  };

  stage(0, 0);
  asm volatile("s_waitcnt vmcnt(0)" ::: "memory");
  asm volatile("s_barrier" ::: "memory");

  for (int t = 0; t < NT; ++t) {
    const int cb = t & 1;
    const int base = cb * BUFSZ;
    if (t + 1 < NT) stage(t + 1, cb ^ 1);
    bf16x8 af[4];
#pragma unroll
    for (int mq = 0; mq < 4; ++mq) {
      int row = wm * 64 + mq * 16 + l15;
      af[mq] = *(const bf16x8*)&lds[base + row * 32 + ((lhi ^ SWZ(row)) * 8)];
    }
#pragma unroll
    for (int w3 = 0; w3 < 3; ++w3) {
      bf16x8 bfr[2];
#pragma unroll
      for (int n = 0; n < 2; ++n) {
        int row = wn * 32 + n * 16 + l15;
        bfr[n] = *(const bf16x8*)&lds[base + 4096 + w3 * 4096 + row * 32 +
                                      ((lhi ^ SWZ(row)) * 8)];
      }
      __builtin_amdgcn_s_setprio(1);
#pragma unroll
      for (int mq = 0; mq < 4; ++mq)
#pragma unroll
        for (int n = 0; n < 2; ++n)
          acc[mq][w3 * 2 + n] = __builtin_amdgcn_mfma_f32_16x16x32_bf16(
              af[mq], bfr[n], acc[mq][w3 * 2 + n], 0, 0, 0);
      __builtin_amdgcn_s_setprio(0);
    }
    asm volatile("s_waitcnt vmcnt(0)" ::: "memory");
    asm volatile("s_barrier" ::: "memory");
  }

  // ---- epilogue part 1: RoPE-fused Q/K stores (round-5 store pattern) ----
  int posr[4][4];
#pragma unroll
  for (int mq = 0; mq < 4; ++mq) {
    int grow = row0 + wm * 64 + mq * 16 + lhi * 4;
#pragma unroll
    for (int j = 0; j < 4; ++j) {
      int r = grow + j;
      posr[mq][j] = tpos[(r >> 11) * SEQ + (r & (SEQ - 1))];
    }
  }
#pragma unroll
  for (int mq = 0; mq < 4; ++mq) {
    int grow = row0 + wm * 64 + mq * 16 + lhi * 4;
#pragma unroll
    for (int n = 0; n < 2; ++n) {
      int gcol = col0 + wn * 32 + n * 16 + l15;
      int h = gcol >> 7, d = gcol & (DK - 1);
      float freq = exp2f(-0.20762050593045976f * (float)(d >> 1));
      bool oddl = (d & 1) != 0;
      float sn[4], cs[4];
#pragma unroll
      for (int j = 0; j < 4; ++j) {
        float ang = (float)posr[mq][j] * freq;
        sn[j] = __sinf(ang);
        cs[j] = __cosf(ang);
      }
#pragma unroll
      for (int w3 = 0; w3 < 2; ++w3) {
        ushort* Ow = w3 ? Ko : Qo;
#pragma unroll
        for (int j = 0; j < 4; ++j) {
          int r = grow + j;
          float v = acc[mq][w3 * 2 + n][j];
          float vp = __shfl_xor(v, 1);
          float outv = oddl ? (vp * sn[j] + v * cs[j]) : (v * cs[j] - vp * sn[j]);
          int b = r >> 11, s = r & (SEQ - 1);
          Ow[((size_t)(b * NH + h) * SEQ + s) * DK + d] = f2bf(outv);
        }
      }
    }
  }

  // ---- epilogue part 2: V transposed via LDS, stride 137 (odd -> ~2-way banks) ----
  {
    ushort* lv = &lds[0];  // 128 x 137; buffers dead after final loop barrier
    __syncthreads();
#pragma unroll
    for (int mq = 0; mq < 4; ++mq)
#pragma unroll
      for (int n = 0; n < 2; ++n) {
        int col = wn * 32 + n * 16 + l15;
#pragma unroll
        for (int j = 0; j < 4; ++j) {
          int rowl = wm * 64 + mq * 16 + lhi * 4 + j;
          lv[rowl * 137 + col] = f2bf(acc[mq][4 + n][j]);
        }
      }
    __syncthreads();
    int b = row0 >> 11, s0r = row0 & (SEQ - 1), h = col0 >> 7;
    ushort* vtbase = Vt + (size_t)(b * NH + h) * DK * SEQ;
#pragma unroll
    for (int cc = 0; cc < 4; ++cc) {
      int c = cc * 512 + tid;        // 0..2047
      int d = c >> 4, scx = (c & 15) * 8;
      ushort8 o;
#pragma unroll
      for (int k = 0; k < 8; ++k) o[k] = lv[(scx + k) * 137 + d];
      *(ushort8*)&vtbase[(size_t)d * SEQ + s0r + scx] = o;
    }
  }
}

// ---- out-proj GEMM: BM=128 BN=256 BK=64, counted vmcnt (unchanged) ----
__global__ __launch_bounds__(512, 2) void gemmF_out(const ushort* __restrict__ A,
                                                    const ushort* __restrict__ Bm,
                                                    float* __restrict__ ofp) {
  extern __shared__ ushort lds[];
  constexpr int NT = DM / 64;
  constexpr int BUFSZ = 8192 + 16384;  // A 128x64 + B 256x64
  int xcd = (int)blockIdx.x & 7, bi = (int)blockIdx.x >> 3;
  int row0 = (((xcd >> 1) << 3) + (bi >> 2)) * 128;
  int col0 = (((xcd & 1) << 2) + (bi & 3)) * 256;
  const int tid = threadIdx.x;
  const int wid = tid >> 6, lane = tid & 63;
  const int l15 = lane & 15, lhi = lane >> 4;
  const int wm = wid >> 2, wn = wid & 3;
  const int swz = l15 & 7;

  f32x4 acc[4][4];
  const f32x4 z4 = {0.f, 0.f, 0.f, 0.f};
#pragma unroll
  for (int mq = 0; mq < 4; ++mq)
#pragma unroll
    for (int i = 0; i < 4; ++i) acc[mq][i] = z4;

  auto stage = [&](int kt, int buf) {
    ushort* dstA = &lds[buf * BUFSZ];
    const ushort* srcA = A + (size_t)row0 * DM + kt * 64;
#pragma unroll
    for (int j = 0; j < 2; ++j) {
      int g = j * 512 + tid;
      int r = g >> 3, c = g & 7;
      GLDS16(srcA + (size_t)r * DM + ((c ^ (r & 7)) * 8),
             &dstA[(j * 512 + wid * 64) * 8]);
    }
    ushort* dstB = &lds[buf * BUFSZ + 8192];
    const ushort* srcB = Bm + (size_t)col0 * DM + kt * 64;
#pragma unroll
    for (int j = 0; j < 4; ++j) {
      int g = j * 512 + tid;
      int r = g >> 3, c = g & 7;
      GLDS16(srcB + (size_t)r * DM + ((c ^ (r & 7)) * 8),
             &dstB[(j * 512 + wid * 64) * 8]);
    }
  };

  stage(0, 0);
  stage(1, 1);

  for (int t = 0; t < NT; ++t) {
    if (t + 1 < NT)
      asm volatile("s_waitcnt vmcnt(6)" ::: "memory");
    else
      asm volatile("s_waitcnt vmcnt(0)" ::: "memory");
    __builtin_amdgcn_s_barrier();

    const int cb = t & 1;
    const ushort* Ab = &lds[cb * BUFSZ];
    const ushort* Bb = Ab + 8192;
#pragma unroll
    for (int ks = 0; ks < 2; ++ks) {
      bf16x8 af[4];
#pragma unroll
      for (int mq = 0; mq < 4; ++mq) {
        int row = wm * 64 + mq * 16 + l15;
        af[mq] = *(const bf16x8*)&Ab[row * 64 + (((ks * 4 + lhi) ^ swz) * 8)];
      }
      bf16x8 bfr[4];
#pragma unroll
      for (int n = 0; n < 4; ++n) {
        int row = wn * 64 + n * 16 + l15;
        bfr[n] = *(const bf16x8*)&Bb[row * 64 + (((ks * 4 + lhi) ^ swz) * 8)];
      }
      __builtin_amdgcn_s_setprio(1);
#pragma unroll
      for (int mq = 0; mq < 4; ++mq)
#pragma unroll
        for (int n = 0; n < 4; ++n)
          acc[mq][n] = __builtin_amdgcn_mfma_f32_16x16x32_bf16(af[mq], bfr[n], acc[mq][n], 0, 0, 0);
      __builtin_amdgcn_s_setprio(0);
    }

    __builtin_amdgcn_s_barrier();
    if (t + 2 < NT) stage(t + 2, cb);
  }

#pragma unroll
  for (int mq = 0; mq < 4; ++mq) {
    int grow = row0 + wm * 64 + mq * 16 + lhi * 4;
#pragma unroll
    for (int n = 0; n < 4; ++n) {
      int gcol = col0 + wn * 64 + n * 16 + l15;
#pragma unroll
      for (int j = 0; j < 4; ++j)
        ofp[(size_t)(grow + j) * DM + gcol] = acc[mq][n][j];
    }
  }
}

// ---------------- flash attention (causal), 4 waves/block, LDS-staged KV ----------------
__global__ __launch_bounds__(256, 2) void attn_kernel(const ushort* __restrict__ Qb,
                                                      const ushort* __restrict__ Kb,
                                                      const ushort* __restrict__ Vt,
                                                      ushort* __restrict__ attnb) {
  __shared__ ushort lds[32768];  // K bufs @0,8192; V^T bufs @16384,24576
  const int bx = blockIdx.x;
  const int u = bx & 255, hg = bx >> 8;
  const int qt = hg ? (15 - (u & 15)) : (u & 15);
  const int bh = (u >> 4) + hg * 16;
  const int tid = threadIdx.x;
  const int w = tid >> 6, lane = tid & 63;
  const int l31 = lane & 31, hi = lane >> 5;
  const int qb = qt * 128;
  const int qsb = qb + w * 32;
  const int q = qsb + l31;
  const size_t qk_base = (size_t)bh * SEQ * DK;
  const size_t v_base = (size_t)bh * DK * SEQ;
  const int nt = (qb + 128) >> 6;

  bf16x8 qf[8];
#pragma unroll
  for (int ks = 0; ks < 8; ++ks)
    qf[ks] = *(const bf16x8*)&Qb[qk_base + (size_t)q * DK + ks * 16 + hi * 8];

  f32x16 acc[4];
#pragma unroll
  for (int dt = 0; dt < 4; ++dt)
#pragma unroll
    for (int r = 0; r < 16; ++r) acc[dt][r] = 0.f;

  float m2 = -INFINITY, lsum = 0.f;
  const float cs2 = 0.08838834764831845f * 1.4426950408889634f;

  auto stage = [&](int t, int bufsel) {
    const int kb0 = t * 64;
#pragma unroll
    for (int i = 0; i < 4; ++i) {
      int g = w * 256 + i * 64 + lane;
      int row = g >> 4, c16 = g & 15;
      GLDS16(Kb + qk_base + (size_t)(kb0 + row) * DK + ((c16 ^ (row & 7)) * 8),
             &lds[bufsel * 8192 + (w * 256 + i * 64) * 8]);
    }
#pragma unroll
    for (int i = 0; i < 4; ++i) {
      int g = w * 256 + i * 64 + lane;
      int row = g >> 3, c8 = g & 7;
      GLDS16(Vt + v_base + (size_t)row * SEQ + kb0 + ((c8 ^ (row & 7)) * 8),
             &lds[16384 + bufsel * 8192 + (w * 256 + i * 64) * 8]);
    }
  };

  stage(0, 0);
  __syncthreads();
  int buf = 0;

  for (int t = 0; t < nt; ++t) {
    if (t + 1 < nt) stage(t + 1, buf ^ 1);
    const int kb0 = t * 64;
    if (kb0 <= qsb) {
      const ushort* lk = &lds[buf * 8192];
      const ushort* lv = &lds[16384 + buf * 8192];
      const int kb1 = kb0 + 32;
      const bool diag0 = (kb0 == qsb);
      const bool have1 = (kb1 <= qsb);
      const bool diag1 = (kb1 == qsb);
      const int sw = l31 & 7;

      f32x16 s0, s1;
#pragma unroll
      for (int r = 0; r < 16; ++r) { s0[r] = 0.f; s1[r] = 0.f; }
      __builtin_amdgcn_s_setprio(1);
#pragma unroll
      for (int ks = 0; ks < 8; ++ks) {
        int g = 2 * ks + hi;
        bf16x8 kf = *(const bf16x8*)&lk[(l31 * 16 + (g ^ sw)) * 8];
        s0 = __builtin_amdgcn_mfma_f32_32x32x16_bf16(kf, qf[ks], s0, 0, 0, 0);
      }
      if (have1) {
#pragma unroll
        for (int ks = 0; ks < 8; ++ks) {
          int g = 2 * ks + hi;
          bf16x8 kf = *(const bf16x8*)&lk[((32 + l31) * 16 + (g ^ sw)) * 8];
          s1 = __builtin_amdgcn_mfma_f32_32x32x16_bf16(kf, qf[ks], s1, 0, 0, 0);
        }
      }
      __builtin_amdgcn_s_setprio(0);

      float mx = -INFINITY;
#pragma unroll
      for (int r = 0; r < 16; ++r) {
        float v = s0[r] * cs2;
        if (diag0) {
          int kk = kb0 + (r & 3) + 8 * (r >> 2) + 4 * hi;
          if (kk > q) v = -INFINITY;
        }
        s0[r] = v;
        mx = fmaxf(mx, v);
      }
      if (have1) {
#pragma unroll
        for (int r = 0; r < 16; ++r) {
          float v = s1[r] * cs2;
          if (diag1) {
            int kk = kb1 + (r & 3) + 8 * (r >> 2) + 4 * hi;
            if (kk > q) v = -INFINITY;
          }
          s1[r] = v;
          mx = fmaxf(mx, v);
        }
      }
      {
        unsigned ma = __builtin_bit_cast(unsigned, mx), mb = ma;
        pswap(ma, mb);
        mx = fmaxf(__builtin_bit_cast(float, ma), __builtin_bit_cast(float, mb));
      }

      float sc = 1.f;
      if (!__all(mx <= m2 + 11.5f)) {
        float mnew = fmaxf(m2, mx);
        sc = exp2f(m2 - mnew);
        m2 = mnew;
#pragma unroll
        for (int dt = 0; dt < 4; ++dt)
#pragma unroll
          for (int r = 0; r < 16; ++r) acc[dt][r] *= sc;
      }
      float rs = 0.f;
#pragma unroll
      for (int r = 0; r < 16; ++r) {
        float p = exp2f(s0[r] - m2);
        s0[r] = p;
        rs += p;
      }
      if (have1) {
#pragma unroll
        for (int r = 0; r < 16; ++r) {
          float p = exp2f(s1[r] - m2);
          s1[r] = p;
          rs += p;
        }
      }
      {
        unsigned ra = __builtin_bit_cast(unsigned, rs), rb = ra;
        pswap(ra, rb);
        rs = __builtin_bit_cast(float, ra) + __builtin_bit_cast(float, rb);
      }
      lsum = lsum * sc + rs;

      unsigned w0[8];
#pragma unroll
      for (int i = 0; i < 8; ++i) w0[i] = cvtpk(s0[2 * i], s0[2 * i + 1]);
      pswap(w0[0], w0[2]); pswap(w0[1], w0[3]);
      pswap(w0[4], w0[6]); pswap(w0[5], w0[7]);
      u32x4 b00 = {w0[0], w0[1], w0[2], w0[3]};
      u32x4 b01 = {w0[4], w0[5], w0[6], w0[7]};
      bf16x8 pb00 = __builtin_bit_cast(bf16x8, b00);
      bf16x8 pb01 = __builtin_bit_cast(bf16x8, b01);
      bf16x8 pb10, pb11;
      if (have1) {
        unsigned w1[8];
#pragma unroll
        for (int i = 0; i < 8; ++i) w1[i] = cvtpk(s1[2 * i], s1[2 * i + 1]);
        pswap(w1[0], w1[2]); pswap(w1[1], w1[3]);
        pswap(w1[4], w1[6]); pswap(w1[5], w1[7]);
        u32x4 b10 = {w1[0], w1[1], w1[2], w1[3]};
        u32x4 b11 = {w1[4], w1[5], w1[6], w1[7]};
        pb10 = __builtin_bit_cast(bf16x8, b10);
        pb11 = __builtin_bit_cast(bf16x8, b11);
      }

      __builtin_amdgcn_s_setprio(1);
#pragma unroll
      for (int dt = 0; dt < 4; ++dt) {
        int vr = (dt * 32 + l31) * 8;
        bf16x8 vf0 = *(const bf16x8*)&lv[(vr + ((0 + hi) ^ sw)) * 8];
        bf16x8 vf1 = *(const bf16x8*)&lv[(vr + ((2 + hi) ^ sw)) * 8];
        acc[dt] = __builtin_amdgcn_mfma_f32_32x32x16_bf16(vf0, pb00, acc[dt], 0, 0, 0);
        acc[dt] = __builtin_amdgcn_mfma_f32_32x32x16_bf16(vf1, pb01, acc[dt], 0, 0, 0);
        if (have1) {
          bf16x8 vf2 = *(const bf16x8*)&lv[(vr + ((4 + hi) ^ sw)) * 8];
          bf16x8 vf3 = *(const bf16x8*)&lv[(vr + ((6 + hi) ^ sw)) * 8];
          acc[dt] = __builtin_amdgcn_mfma_f32_32x32x16_bf16(vf2, pb10, acc[dt], 0, 0, 0);
          acc[dt] = __builtin_amdgcn_mfma_f32_32x32x16_bf16(vf3, pb11, acc[dt], 0, 0, 0);
        }
      }
      __builtin_amdgcn_s_setprio(0);
    }
    __syncthreads();
    buf ^= 1;
  }

  ushort* eo = &lds[w * 32 * 136];
  float inv = 1.0f / lsum;
#pragma unroll
  for (int dt = 0; dt < 4; ++dt)
#pragma unroll
    for (int rq = 0; rq < 4; ++rq) {
      unsigned lo = cvtpk(acc[dt][4 * rq] * inv, acc[dt][4 * rq + 1] * inv);
      unsigned hh = cvtpk(acc[dt][4 * rq + 2] * inv, acc[dt][4 * rq + 3] * inv);
      uint2 pr; pr.x = lo; pr.y = hh;
      *(uint2*)&eo[l31 * 136 + dt * 32 + rq * 8 + hi * 4] = pr;
    }
  const int b = bh >> 4, h = bh & (NH - 1);
#pragma unroll
  for (int it = 0; it < 8; ++it) {
    int row = it * 4 + (lane >> 4);
    int c8 = (lane & 15) * 8;
    ushort8 v = *(const ushort8*)&eo[row * 136 + c8];
    *(ushort8*)&attnb[((size_t)b * SEQ + qsb + row) * DM + h * DK + c8] = v;
  }
}

extern "C" void kernel_launch(void* const* d_in, const int* in_sizes, int n_in,
                              void* d_out, int out_size, void* d_ws, size_t ws_size,
                              hipStream_t stream) {
  const float* x = (const float*)d_in[0];
  const int* tpos = (const int*)d_in[1];
  const float* WQ = (const float*)d_in[2];
  const float* WK = (const float*)d_in[3];
  const float* WV = (const float*)d_in[4];
  const float* WO = (const float*)d_in[5];
  float* out = (float*)d_out;
  char* ws = (char*)d_ws;

  ushort* xb  = (ushort*)(ws + 0);           // dead after QKV gemm
  ushort* wqb = (ushort*)(ws + 16777216);
  ushort* wkb = (ushort*)(ws + 25165824);
  ushort* wvb = (ushort*)(ws + 33554432);
  ushort* wob = (ushort*)(ws + 41943040);
  ushort* Qb  = (ushort*)(ws + 50331648);
  ushort* Kb  = (ushort*)(ws + 67108864);
  ushort* Vt  = (ushort*)(ws + 83886080);    // written transposed by qkv epilogue
  ushort* attnb = (ushort*)(ws + 16777216);  // alias wqb+wkb (dead after attn input gen)

  hipFuncSetAttribute(reinterpret_cast<const void*>(gemmF_qkv),
                      hipFuncAttributeMaxDynamicSharedMemorySize, 65536);
  hipFuncSetAttribute(reinterpret_cast<const void*>(gemmF_out),
                      hipFuncAttributeMaxDynamicSharedMemorySize, 98304);

  cvt_all<<<12288, 256, 0, stream>>>(x, WQ, WK, WV, WO, xb, wqb, wkb, wvb, wob);

  gemmF_qkv<<<512, 512, 65536, stream>>>(xb, wqb, wkb, wvb, Qb, Kb, Vt, tpos);

  attn_kernel<<<dim3(512), 256, 0, stream>>>(Qb, Kb, Vt, attnb);

  gemmF_out<<<256, 512, 98304, stream>>>(attnb, wob, out);
}

// Round 16
// 232.009 us; speedup vs baseline: 1.1016x; 1.1016x over previous
//
#include <hip/hip_runtime.h>

typedef unsigned short ushort;
typedef __attribute__((ext_vector_type(8))) __bf16 bf16x8;
typedef __attribute__((ext_vector_type(8))) ushort ushort8;
typedef __attribute__((ext_vector_type(4))) float f32x4;
typedef __attribute__((ext_vector_type(16))) float f32x16;
typedef __attribute__((ext_vector_type(4))) unsigned u32x4;

#define DM 2048
#define NH 16
#define DK 128
#define BATCH 2
#define SEQ 2048
#define MROWS (BATCH*SEQ)   // 4096

#define GLDS16(g, l) __builtin_amdgcn_global_load_lds(                         \
    (const __attribute__((address_space(1))) void*)(g),                        \
    (__attribute__((address_space(3))) void*)(l), 16, 0, 0)

__device__ __forceinline__ ushort f2bf(float f) {
  unsigned u = __builtin_bit_cast(unsigned, f);
  u += 0x7fffu + ((u >> 16) & 1u);
  return (ushort)(u >> 16);
}

__device__ __forceinline__ unsigned cvtpk(float lo, float hi) {
  unsigned r;
  asm("v_cvt_pk_bf16_f32 %0, %1, %2" : "=v"(r) : "v"(lo), "v"(hi));
  return r;
}

// permlane32_swap: a' = [a.lo32 | b.lo32], b' = [a.hi32 | b.hi32]
__device__ __forceinline__ void pswap(unsigned& a, unsigned& b) {
#if __has_builtin(__builtin_amdgcn_permlane32_swap)
  auto r = __builtin_amdgcn_permlane32_swap(a, b, false, false);
  a = r[0];
  b = r[1];
#else
  unsigned as = (unsigned)__shfl_xor((int)a, 32), bs = (unsigned)__shfl_xor((int)b, 32);
  bool hi = (threadIdx.x & 32) != 0;
  unsigned na = hi ? bs : a;
  unsigned nb = hi ? b : as;
  a = na;
  b = nb;
#endif
}

// ---------------- f32 -> bf16 convert (x + 4 weights, one launch) ----------------
__global__ __launch_bounds__(256) void cvt_all(const float* __restrict__ x,
                                               const float* __restrict__ w0,
                                               const float* __restrict__ w1,
                                               const float* __restrict__ w2,
                                               const float* __restrict__ w3,
                                               ushort* __restrict__ xb,
                                               ushort* __restrict__ o0,
                                               ushort* __restrict__ o1,
                                               ushort* __restrict__ o2,
                                               ushort* __restrict__ o3) {
  int b = blockIdx.x;
  const float* src;
  ushort* dst;
  int lb;
  if (b < 4096) { src = x; dst = xb; lb = b; }
  else {
    int wsel = (b - 4096) >> 11;
    lb = (b - 4096) & 2047;
    src = (wsel == 0) ? w0 : (wsel == 1) ? w1 : (wsel == 2) ? w2 : w3;
    dst = (wsel == 0) ? o0 : (wsel == 1) ? o1 : (wsel == 2) ? o2 : o3;
  }
  int i = lb * 256 + threadIdx.x;
  const float4* p = (const float4*)src;
  float4 a = p[2 * i], bq = p[2 * i + 1];
  ushort8 o;
  o[0] = f2bf(a.x); o[1] = f2bf(a.y); o[2] = f2bf(a.z); o[3] = f2bf(a.w);
  o[4] = f2bf(bq.x); o[5] = f2bf(bq.y); o[6] = f2bf(bq.z); o[7] = f2bf(bq.w);
  *(ushort8*)(dst + (size_t)8 * i) = o;
}

// ---- fused QKV GEMM (round-5 exact core), BM=128, BK=64, 8 waves (2M x 4N) ----
// Epilogue: RoPE on Q/K (in-register rotation, fast __sinf/__cosf) with round-5's
// clean store pattern, and V written DIRECTLY TRANSPOSED via an LDS re-transpose.
// V-transpose LDS stride 137 (odd): breaks the 16-way gather conflict of 136.
__global__ __launch_bounds__(512, 2) void gemmF_qkv(const ushort* __restrict__ A,
                                                    const ushort* __restrict__ W0,
                                                    const ushort* __restrict__ W1,
                                                    const ushort* __restrict__ W2,
                                                    ushort* __restrict__ Qo,
                                                    ushort* __restrict__ Ko,
                                                    ushort* __restrict__ Vt,
                                                    const int* __restrict__ tpos) {
  extern __shared__ ushort lds[];
  constexpr int NT = DM / 64;          // 32 K-tiles
  constexpr int BUFSZ = 8192 + 24576;  // A 128x64 + 3x B 128x64 (ushorts)
  // 512 blocks; XCD-bijective swizzle (chunk 64) — round-5 mapping
  int f = ((int)blockIdx.x & 7) * 64 + ((int)blockIdx.x >> 3);
  int row0 = (f >> 4) * 128, col0 = (f & 15) * 128;
  const ushort* Bw[3] = {W0, W1, W2};
  const int tid = threadIdx.x;
  const int wid = tid >> 6, lane = tid & 63;
  const int l15 = lane & 15, lhi = lane >> 4;
  const int wm = wid >> 2, wn = wid & 3;
  const int swz = l15 & 7;

  f32x4 acc[4][6];
  const f32x4 z4 = {0.f, 0.f, 0.f, 0.f};
#pragma unroll
  for (int mq = 0; mq < 4; ++mq)
#pragma unroll
    for (int i = 0; i < 6; ++i) acc[mq][i] = z4;

  auto stage = [&](int kt, int buf) {
    ushort* dstA = &lds[buf * BUFSZ];
    const ushort* srcA = A + (size_t)row0 * DM + kt * 64;
#pragma unroll
    for (int j = 0; j < 2; ++j) {
      int g = j * 512 + tid;
      int r = g >> 3, c = g & 7;
      GLDS16(srcA + (size_t)r * DM + ((c ^ (r & 7)) * 8),
             &dstA[(j * 512 + wid * 64) * 8]);
    }
#pragma unroll
    for (int w3 = 0; w3 < 3; ++w3) {
      ushort* dstB = &lds[buf * BUFSZ + 8192 + w3 * 8192];
      const ushort* srcB = Bw[w3] + (size_t)col0 * DM + kt * 64;
#pragma unroll
      for (int j = 0; j < 2; ++j) {
        int g = j * 512 + tid;
        int r = g >> 3, c = g & 7;
        GLDS16(srcB + (size_t)r * DM + ((c ^ (r & 7)) * 8),
               &dstB[(j * 512 + wid * 64) * 8]);
      }
    }
  };

  stage(0, 0);
  asm volatile("s_waitcnt vmcnt(0)" ::: "memory");
  asm volatile("s_barrier" ::: "memory");

  for (int t = 0; t < NT; ++t) {
    const int cb = t & 1;
    const ushort* Ab = &lds[cb * BUFSZ];
    const ushort* Bb = Ab + 8192;
    if (t + 1 < NT) stage(t + 1, cb ^ 1);
#pragma unroll
    for (int ks = 0; ks < 2; ++ks) {
      bf16x8 af[4];
#pragma unroll
      for (int mq = 0; mq < 4; ++mq) {
        int row = wm * 64 + mq * 16 + l15;
        af[mq] = *(const bf16x8*)&Ab[row * 64 + (((ks * 4 + lhi) ^ swz) * 8)];
      }
      bf16x8 bfr[6];
#pragma unroll
      for (int w3 = 0; w3 < 3; ++w3)
#pragma unroll
        for (int n = 0; n < 2; ++n) {
          int row = wn * 32 + n * 16 + l15;
          bfr[w3 * 2 + n] =
              *(const bf16x8*)&Bb[w3 * 8192 + row * 64 + (((ks * 4 + lhi) ^ swz) * 8)];
        }
      __builtin_amdgcn_s_setprio(1);
#pragma unroll
      for (int mq = 0; mq < 4; ++mq)
#pragma unroll
        for (int i = 0; i < 6; ++i)
          acc[mq][i] = __builtin_amdgcn_mfma_f32_16x16x32_bf16(af[mq], bfr[i], acc[mq][i], 0, 0, 0);
      __builtin_amdgcn_s_setprio(0);
    }
    asm volatile("s_waitcnt vmcnt(0)" ::: "memory");
    asm volatile("s_barrier" ::: "memory");
  }

  // ---- epilogue part 1: RoPE-fused Q/K stores (round-5 store pattern) ----
  int posr[4][4];
#pragma unroll
  for (int mq = 0; mq < 4; ++mq) {
    int grow = row0 + wm * 64 + mq * 16 + lhi * 4;
#pragma unroll
    for (int j = 0; j < 4; ++j) {
      int r = grow + j;
      posr[mq][j] = tpos[(r >> 11) * SEQ + (r & (SEQ - 1))];
    }
  }
#pragma unroll
  for (int mq = 0; mq < 4; ++mq) {
    int grow = row0 + wm * 64 + mq * 16 + lhi * 4;
#pragma unroll
    for (int n = 0; n < 2; ++n) {
      int gcol = col0 + wn * 32 + n * 16 + l15;
      int h = gcol >> 7, d = gcol & (DK - 1);
      float freq = exp2f(-0.20762050593045976f * (float)(d >> 1));
      bool oddl = (d & 1) != 0;
      float sn[4], cs[4];
#pragma unroll
      for (int j = 0; j < 4; ++j) {
        float ang = (float)posr[mq][j] * freq;
        sn[j] = __sinf(ang);
        cs[j] = __cosf(ang);
      }
#pragma unroll
      for (int w3 = 0; w3 < 2; ++w3) {
        ushort* Ow = w3 ? Ko : Qo;
#pragma unroll
        for (int j = 0; j < 4; ++j) {
          int r = grow + j;
          float v = acc[mq][w3 * 2 + n][j];
          float vp = __shfl_xor(v, 1);
          float outv = oddl ? (vp * sn[j] + v * cs[j]) : (v * cs[j] - vp * sn[j]);
          int b = r >> 11, s = r & (SEQ - 1);
          Ow[((size_t)(b * NH + h) * SEQ + s) * DK + d] = f2bf(outv);
        }
      }
    }
  }

  // ---- epilogue part 2: V transposed via LDS, stride 137 (odd -> ~2-way banks) ----
  {
    ushort* lv = &lds[0];  // 128 x 137; buffer 0 dead after final loop barrier
#pragma unroll
    for (int mq = 0; mq < 4; ++mq)
#pragma unroll
      for (int n = 0; n < 2; ++n) {
        int col = wn * 32 + n * 16 + l15;
#pragma unroll
        for (int j = 0; j < 4; ++j) {
          int rowl = wm * 64 + mq * 16 + lhi * 4 + j;
          lv[rowl * 137 + col] = f2bf(acc[mq][4 + n][j]);
        }
      }
    __syncthreads();
    int b = row0 >> 11, s0r = row0 & (SEQ - 1), h = col0 >> 7;
    ushort* vtbase = Vt + (size_t)(b * NH + h) * DK * SEQ;
#pragma unroll
    for (int cc = 0; cc < 4; ++cc) {
      int c = cc * 512 + tid;        // 0..2047
      int d = c >> 4, sc = (c & 15) * 8;
      ushort8 o;
#pragma unroll
      for (int k = 0; k < 8; ++k) o[k] = lv[(sc + k) * 137 + d];
      *(ushort8*)&vtbase[(size_t)d * SEQ + s0r + sc] = o;
    }
  }
}

// ---- out-proj GEMM: BM=128 BN=256 BK=64, counted vmcnt ----
__global__ __launch_bounds__(512, 2) void gemmF_out(const ushort* __restrict__ A,
                                                    const ushort* __restrict__ Bm,
                                                    float* __restrict__ ofp) {
  extern __shared__ ushort lds[];
  constexpr int NT = DM / 64;
  constexpr int BUFSZ = 8192 + 16384;  // A 128x64 + B 256x64
  // 256 blocks, grid 32r x 8c; XCD owns an 8-row x 4-col chunk
  int xcd = (int)blockIdx.x & 7, bi = (int)blockIdx.x >> 3;
  int row0 = (((xcd >> 1) << 3) + (bi >> 2)) * 128;
  int col0 = (((xcd & 1) << 2) + (bi & 3)) * 256;
  const int tid = threadIdx.x;
  const int wid = tid >> 6, lane = tid & 63;
  const int l15 = lane & 15, lhi = lane >> 4;
  const int wm = wid >> 2, wn = wid & 3;
  const int swz = l15 & 7;

  f32x4 acc[4][4];
  const f32x4 z4 = {0.f, 0.f, 0.f, 0.f};
#pragma unroll
  for (int mq = 0; mq < 4; ++mq)
#pragma unroll
    for (int i = 0; i < 4; ++i) acc[mq][i] = z4;

  auto stage = [&](int kt, int buf) {
    ushort* dstA = &lds[buf * BUFSZ];
    const ushort* srcA = A + (size_t)row0 * DM + kt * 64;
#pragma unroll
    for (int j = 0; j < 2; ++j) {
      int g = j * 512 + tid;
      int r = g >> 3, c = g & 7;
      GLDS16(srcA + (size_t)r * DM + ((c ^ (r & 7)) * 8),
             &dstA[(j * 512 + wid * 64) * 8]);
    }
    ushort* dstB = &lds[buf * BUFSZ + 8192];
    const ushort* srcB = Bm + (size_t)col0 * DM + kt * 64;
#pragma unroll
    for (int j = 0; j < 4; ++j) {
      int g = j * 512 + tid;
      int r = g >> 3, c = g & 7;
      GLDS16(srcB + (size_t)r * DM + ((c ^ (r & 7)) * 8),
             &dstB[(j * 512 + wid * 64) * 8]);
    }
  };

  stage(0, 0);
  stage(1, 1);

  for (int t = 0; t < NT; ++t) {
    if (t + 1 < NT)
      asm volatile("s_waitcnt vmcnt(6)" ::: "memory");
    else
      asm volatile("s_waitcnt vmcnt(0)" ::: "memory");
    __builtin_amdgcn_s_barrier();

    const int cb = t & 1;
    const ushort* Ab = &lds[cb * BUFSZ];
    const ushort* Bb = Ab + 8192;
#pragma unroll
    for (int ks = 0; ks < 2; ++ks) {
      bf16x8 af[4];
#pragma unroll
      for (int mq = 0; mq < 4; ++mq) {
        int row = wm * 64 + mq * 16 + l15;
        af[mq] = *(const bf16x8*)&Ab[row * 64 + (((ks * 4 + lhi) ^ swz) * 8)];
      }
      bf16x8 bfr[4];
#pragma unroll
      for (int n = 0; n < 4; ++n) {
        int row = wn * 64 + n * 16 + l15;
        bfr[n] = *(const bf16x8*)&Bb[row * 64 + (((ks * 4 + lhi) ^ swz) * 8)];
      }
      __builtin_amdgcn_s_setprio(1);
#pragma unroll
      for (int mq = 0; mq < 4; ++mq)
#pragma unroll
        for (int n = 0; n < 4; ++n)
          acc[mq][n] = __builtin_amdgcn_mfma_f32_16x16x32_bf16(af[mq], bfr[n], acc[mq][n], 0, 0, 0);
      __builtin_amdgcn_s_setprio(0);
    }

    __builtin_amdgcn_s_barrier();
    if (t + 2 < NT) stage(t + 2, cb);
  }

#pragma unroll
  for (int mq = 0; mq < 4; ++mq) {
    int grow = row0 + wm * 64 + mq * 16 + lhi * 4;
#pragma unroll
    for (int n = 0; n < 4; ++n) {
      int gcol = col0 + wn * 64 + n * 16 + l15;
#pragma unroll
      for (int j = 0; j < 4; ++j)
        ofp[(size_t)(grow + j) * DM + gcol] = acc[mq][n][j];
    }
  }
}

// ---------------- flash attention (causal), 4 waves/block, LDS-staged KV ----------------
__global__ __launch_bounds__(256, 2) void attn_kernel(const ushort* __restrict__ Qb,
                                                      const ushort* __restrict__ Kb,
                                                      const ushort* __restrict__ Vt,
                                                      ushort* __restrict__ attnb) {
  __shared__ ushort lds[32768];  // K bufs @0,8192; V^T bufs @16384,24576
  const int bx = blockIdx.x;
  const int u = bx & 255, hg = bx >> 8;
  const int qt = hg ? (15 - (u & 15)) : (u & 15);
  const int bh = (u >> 4) + hg * 16;
  const int tid = threadIdx.x;
  const int w = tid >> 6, lane = tid & 63;
  const int l31 = lane & 31, hi = lane >> 5;
  const int qb = qt * 128;
  const int qsb = qb + w * 32;
  const int q = qsb + l31;
  const size_t qk_base = (size_t)bh * SEQ * DK;
  const size_t v_base = (size_t)bh * DK * SEQ;
  const int nt = (qb + 128) >> 6;

  bf16x8 qf[8];
#pragma unroll
  for (int ks = 0; ks < 8; ++ks)
    qf[ks] = *(const bf16x8*)&Qb[qk_base + (size_t)q * DK + ks * 16 + hi * 8];

  f32x16 acc[4];
#pragma unroll
  for (int dt = 0; dt < 4; ++dt)
#pragma unroll
    for (int r = 0; r < 16; ++r) acc[dt][r] = 0.f;

  float m2 = -INFINITY, lsum = 0.f;
  const float cs2 = 0.08838834764831845f * 1.4426950408889634f;

  auto stage = [&](int t, int bufsel) {
    const int kb0 = t * 64;
#pragma unroll
    for (int i = 0; i < 4; ++i) {
      int g = w * 256 + i * 64 + lane;
      int row = g >> 4, c16 = g & 15;
      GLDS16(Kb + qk_base + (size_t)(kb0 + row) * DK + ((c16 ^ (row & 7)) * 8),
             &lds[bufsel * 8192 + (w * 256 + i * 64) * 8]);
    }
#pragma unroll
    for (int i = 0; i < 4; ++i) {
      int g = w * 256 + i * 64 + lane;
      int row = g >> 3, c8 = g & 7;
      GLDS16(Vt + v_base + (size_t)row * SEQ + kb0 + ((c8 ^ (row & 7)) * 8),
             &lds[16384 + bufsel * 8192 + (w * 256 + i * 64) * 8]);
    }
  };

  stage(0, 0);
  __syncthreads();
  int buf = 0;

  for (int t = 0; t < nt; ++t) {
    if (t + 1 < nt) stage(t + 1, buf ^ 1);
    const int kb0 = t * 64;
    if (kb0 <= qsb) {
      const ushort* lk = &lds[buf * 8192];
      const ushort* lv = &lds[16384 + buf * 8192];
      const int kb1 = kb0 + 32;
      const bool diag0 = (kb0 == qsb);
      const bool have1 = (kb1 <= qsb);
      const bool diag1 = (kb1 == qsb);
      const int sw = l31 & 7;

      f32x16 s0, s1;
#pragma unroll
      for (int r = 0; r < 16; ++r) { s0[r] = 0.f; s1[r] = 0.f; }
      __builtin_amdgcn_s_setprio(1);
#pragma unroll
      for (int ks = 0; ks < 8; ++ks) {
        int g = 2 * ks + hi;
        bf16x8 kf = *(const bf16x8*)&lk[(l31 * 16 + (g ^ sw)) * 8];
        s0 = __builtin_amdgcn_mfma_f32_32x32x16_bf16(kf, qf[ks], s0, 0, 0, 0);
      }
      if (have1) {
#pragma unroll
        for (int ks = 0; ks < 8; ++ks) {
          int g = 2 * ks + hi;
          bf16x8 kf = *(const bf16x8*)&lk[((32 + l31) * 16 + (g ^ sw)) * 8];
          s1 = __builtin_amdgcn_mfma_f32_32x32x16_bf16(kf, qf[ks], s1, 0, 0, 0);
        }
      }
      __builtin_amdgcn_s_setprio(0);

      float mx = -INFINITY;
#pragma unroll
      for (int r = 0; r < 16; ++r) {
        float v = s0[r] * cs2;
        if (diag0) {
          int kk = kb0 + (r & 3) + 8 * (r >> 2) + 4 * hi;
          if (kk > q) v = -INFINITY;
        }
        s0[r] = v;
        mx = fmaxf(mx, v);
      }
      if (have1) {
#pragma unroll
        for (int r = 0; r < 16; ++r) {
          float v = s1[r] * cs2;
          if (diag1) {
            int kk = kb1 + (r & 3) + 8 * (r >> 2) + 4 * hi;
            if (kk > q) v = -INFINITY;
          }
          s1[r] = v;
          mx = fmaxf(mx, v);
        }
      }
      {
        unsigned ma = __builtin_bit_cast(unsigned, mx), mb = ma;
        pswap(ma, mb);
        mx = fmaxf(__builtin_bit_cast(float, ma), __builtin_bit_cast(float, mb));
      }

      float sc = 1.f;
      if (!__all(mx <= m2 + 11.5f)) {
        float mnew = fmaxf(m2, mx);
        sc = exp2f(m2 - mnew);
        m2 = mnew;
#pragma unroll
        for (int dt = 0; dt < 4; ++dt)
#pragma unroll
          for (int r = 0; r < 16; ++r) acc[dt][r] *= sc;
      }
      float rs = 0.f;
#pragma unroll
      for (int r = 0; r < 16; ++r) {
        float p = exp2f(s0[r] - m2);
        s0[r] = p;
        rs += p;
      }
      if (have1) {
#pragma unroll
        for (int r = 0; r < 16; ++r) {
          float p = exp2f(s1[r] - m2);
          s1[r] = p;
          rs += p;
        }
      }
      {
        unsigned ra = __builtin_bit_cast(unsigned, rs), rb = ra;
        pswap(ra, rb);
        rs = __builtin_bit_cast(float, ra) + __builtin_bit_cast(float, rb);
      }
      lsum = lsum * sc + rs;

      unsigned w0[8];
#pragma unroll
      for (int i = 0; i < 8; ++i) w0[i] = cvtpk(s0[2 * i], s0[2 * i + 1]);
      pswap(w0[0], w0[2]); pswap(w0[1], w0[3]);
      pswap(w0[4], w0[6]); pswap(w0[5], w0[7]);
      u32x4 b00 = {w0[0], w0[1], w0[2], w0[3]};
      u32x4 b01 = {w0[4], w0[5], w0[6], w0[7]};
      bf16x8 pb00 = __builtin_bit_cast(bf16x8, b00);
      bf16x8 pb01 = __builtin_bit_cast(bf16x8, b01);
      bf16x8 pb10, pb11;
      if (have1) {
        unsigned w1[8];
#pragma unroll
        for (int i = 0; i < 8; ++i) w1[i] = cvtpk(s1[2 * i], s1[2 * i + 1]);
        pswap(w1[0], w1[2]); pswap(w1[1], w1[3]);
        pswap(w1[4], w1[6]); pswap(w1[5], w1[7]);
        u32x4 b10 = {w1[0], w1[1], w1[2], w1[3]};
        u32x4 b11 = {w1[4], w1[5], w1[6], w1[7]};
        pb10 = __builtin_bit_cast(bf16x8, b10);
        pb11 = __builtin_bit_cast(bf16x8, b11);
      }

      __builtin_amdgcn_s_setprio(1);
#pragma unroll
      for (int dt = 0; dt < 4; ++dt) {
        int vr = (dt * 32 + l31) * 8;
        bf16x8 vf0 = *(const bf16x8*)&lv[(vr + ((0 + hi) ^ sw)) * 8];
        bf16x8 vf1 = *(const bf16x8*)&lv[(vr + ((2 + hi) ^ sw)) * 8];
        acc[dt] = __builtin_amdgcn_mfma_f32_32x32x16_bf16(vf0, pb00, acc[dt], 0, 0, 0);
        acc[dt] = __builtin_amdgcn_mfma_f32_32x32x16_bf16(vf1, pb01, acc[dt], 0, 0, 0);
        if (have1) {
          bf16x8 vf2 = *(const bf16x8*)&lv[(vr + ((4 + hi) ^ sw)) * 8];
          bf16x8 vf3 = *(const bf16x8*)&lv[(vr + ((6 + hi) ^ sw)) * 8];
          acc[dt] = __builtin_amdgcn_mfma_f32_32x32x16_bf16(vf2, pb10, acc[dt], 0, 0, 0);
          acc[dt] = __builtin_amdgcn_mfma_f32_32x32x16_bf16(vf3, pb11, acc[dt], 0, 0, 0);
        }
      }
      __builtin_amdgcn_s_setprio(0);
    }
    __syncthreads();
    buf ^= 1;
  }

  ushort* eo = &lds[w * 32 * 136];
  float inv = 1.0f / lsum;
#pragma unroll
  for (int dt = 0; dt < 4; ++dt)
#pragma unroll
    for (int rq = 0; rq < 4; ++rq) {
      unsigned lo = cvtpk(acc[dt][4 * rq] * inv, acc[dt][4 * rq + 1] * inv);
      unsigned hh = cvtpk(acc[dt][4 * rq + 2] * inv, acc[dt][4 * rq + 3] * inv);
      uint2 pr; pr.x = lo; pr.y = hh;
      *(uint2*)&eo[l31 * 136 + dt * 32 + rq * 8 + hi * 4] = pr;
    }
  const int b = bh >> 4, h = bh & (NH - 1);
#pragma unroll
  for (int it = 0; it < 8; ++it) {
    int row = it * 4 + (lane >> 4);
    int c8 = (lane & 15) * 8;
    ushort8 v = *(const ushort8*)&eo[row * 136 + c8];
    *(ushort8*)&attnb[((size_t)b * SEQ + qsb + row) * DM + h * DK + c8] = v;
  }
}

extern "C" void kernel_launch(void* const* d_in, const int* in_sizes, int n_in,
                              void* d_out, int out_size, void* d_ws, size_t ws_size,
                              hipStream_t stream) {
  const float* x = (const float*)d_in[0];
  const int* tpos = (const int*)d_in[1];
  const float* WQ = (const float*)d_in[2];
  const float* WK = (const float*)d_in[3];
  const float* WV = (const float*)d_in[4];
  const float* WO = (const float*)d_in[5];
  float* out = (float*)d_out;
  char* ws = (char*)d_ws;

  ushort* xb  = (ushort*)(ws + 0);           // dead after QKV gemm
  ushort* wqb = (ushort*)(ws + 16777216);
  ushort* wkb = (ushort*)(ws + 25165824);
  ushort* wvb = (ushort*)(ws + 33554432);
  ushort* wob = (ushort*)(ws + 41943040);
  ushort* Qb  = (ushort*)(ws + 50331648);
  ushort* Kb  = (ushort*)(ws + 67108864);
  ushort* Vt  = (ushort*)(ws + 83886080);    // written transposed by qkv epilogue
  ushort* attnb = (ushort*)(ws + 16777216);  // alias wqb+wkb (dead after attn input gen)

  hipFuncSetAttribute(reinterpret_cast<const void*>(gemmF_qkv),
                      hipFuncAttributeMaxDynamicSharedMemorySize, 131072);
  hipFuncSetAttribute(reinterpret_cast<const void*>(gemmF_out),
                      hipFuncAttributeMaxDynamicSharedMemorySize, 98304);

  cvt_all<<<12288, 256, 0, stream>>>(x, WQ, WK, WV, WO, xb, wqb, wkb, wvb, wob);

  gemmF_qkv<<<512, 512, 131072, stream>>>(xb, wqb, wkb, wvb, Qb, Kb, Vt, tpos);

  attn_kernel<<<dim3(512), 256, 0, stream>>>(Qb, Kb, Vt, attnb);

  gemmF_out<<<256, 512, 98304, stream>>>(attnb, wob, out);
}